// Round 3
// baseline (47.723 us; speedup 1.0000x reference)
//
#include <hip/hip_runtime.h>

// IFNode multi-step forward, hard reset.
// x: (T=16, N=32, F=65536) f32. out: spikes, same shape/dtype.
// Per (n,f): v=0; for t: h=v+x[t]; spike=(h>=1); v = spike?0:h; out[t]=spike.
//
// Round-2 insight: working set = 128MiB in + 128MiB out = 262MiB, 9MiB over
// the 256MiB Infinity Cache -> ~half the input (65.5MB) refetches from HBM
// every replay, at a fixed ~4.3 TB/s effective BW. Writes are irreducible;
// the fetch is not: nontemporal-load a 1/4 slice of the input so the other
// 96MiB of input + 128MiB output (224MiB) stays L3-resident. Expected HBM
// traffic 196 -> ~165MB.

#define T_STEPS 16

typedef float v4f __attribute__((ext_vector_type(4)));

template <bool NT_LOAD>
__device__ __forceinline__ void ifnode_chain(
    const v4f* __restrict__ x4, v4f* __restrict__ o4, int nf4, int idx) {
    v4f v = {0.f, 0.f, 0.f, 0.f};

#pragma unroll
    for (int t = 0; t < T_STEPS; ++t) {
        const v4f* p = &x4[(size_t)t * nf4 + idx];
        v4f xv = NT_LOAD ? __builtin_nontemporal_load(p) : *p;
        v4f s;

        float h;
        h = v.x + xv.x; s.x = (h >= 1.0f) ? 1.0f : 0.0f; v.x = (h >= 1.0f) ? 0.0f : h;
        h = v.y + xv.y; s.y = (h >= 1.0f) ? 1.0f : 0.0f; v.y = (h >= 1.0f) ? 0.0f : h;
        h = v.z + xv.z; s.z = (h >= 1.0f) ? 1.0f : 0.0f; v.z = (h >= 1.0f) ? 0.0f : h;
        h = v.w + xv.w; s.w = (h >= 1.0f) ? 1.0f : 0.0f; v.w = (h >= 1.0f) ? 0.0f : h;

        __builtin_nontemporal_store(s, &o4[(size_t)t * nf4 + idx]);
    }
}

__global__ __launch_bounds__(256) void ifnode_kernel(
    const v4f* __restrict__ x4, v4f* __restrict__ o4, int nf4, int nt_cut) {
    int idx = blockIdx.x * blockDim.x + threadIdx.x;
    if (idx >= nf4) return;

    if (idx < nt_cut) {
        ifnode_chain<true>(x4, o4, nf4, idx);   // nt slice: never cached
    } else {
        ifnode_chain<false>(x4, o4, nf4, idx);  // cached slice: L3-resident
    }
}

extern "C" void kernel_launch(void* const* d_in, const int* in_sizes, int n_in,
                              void* d_out, int out_size, void* d_ws, size_t ws_size,
                              hipStream_t stream) {
    const float* x = (const float*)d_in[0];
    float* out = (float*)d_out;

    int nf = in_sizes[0] / T_STEPS;   // 32*65536 = 2097152
    int nf4 = nf / 4;                 // 524288 v4f elements per step

    int nt_cut = nf4 / 4;             // 1/4 of input (32MiB) streams via nt loads

    int block = 256;
    int grid = (nf4 + block - 1) / block;  // 2048

    ifnode_kernel<<<grid, block, 0, stream>>>(
        (const v4f*)x, (v4f*)out, nf4, nt_cut);
}